// Round 1
// baseline (650.307 us; speedup 1.0000x reference)
//
#include <hip/hip_runtime.h>
#include <hip/hip_bf16.h>
#include <stdint.h>

// out[m,n] = sum_k x[m,k] * (W[n,k] + sum_r down[n,r]*up[r,k]) + bias[n]
// M=8192 (B*S), N=4096 (OUT), K=4096 (IN), R=16. All fp32 I/O.
// Strategy: convert x and merged weight to bf16 in d_ws, then m97-style
// bf16 MFMA gemm_bt (both operands K-major) with fused bias epilogue.

typedef __attribute__((ext_vector_type(4))) float  floatx4;
typedef __attribute__((ext_vector_type(8))) __bf16 bf16x8;

static __device__ __forceinline__ unsigned short f2bf_rne(float f) {
    union { float f; uint32_t u; } v; v.f = f;
    uint32_t r = v.u + 0x7fffu + ((v.u >> 16) & 1u);
    return (unsigned short)(r >> 16);
}

// ---------------- x fp32 -> bf16 (8 elems/thread) ----------------
__global__ __launch_bounds__(256) void cvt_x_kernel(const float* __restrict__ x,
                                                    unsigned short* __restrict__ xb,
                                                    int n) {
    int i = (blockIdx.x * 256 + threadIdx.x) * 8;
    if (i >= n) return;
    const float4* p = (const float4*)(x + i);
    float4 a = p[0], b = p[1];
    union { unsigned short s[8]; uint4 v; } o;
    o.s[0] = f2bf_rne(a.x); o.s[1] = f2bf_rne(a.y);
    o.s[2] = f2bf_rne(a.z); o.s[3] = f2bf_rne(a.w);
    o.s[4] = f2bf_rne(b.x); o.s[5] = f2bf_rne(b.y);
    o.s[6] = f2bf_rne(b.z); o.s[7] = f2bf_rne(b.w);
    *(uint4*)(xb + i) = o.v;
}

// ------------- merged weight: Wb[n,k] = bf16(W[n,k] + sum_r d[n,r]*up[r,k]) -------------
__global__ __launch_bounds__(256) void merge_w_kernel(const float* __restrict__ W,
                                                      const float* __restrict__ down,
                                                      const float* __restrict__ up,
                                                      unsigned short* __restrict__ wb,
                                                      int IN) {
    const int o = blockIdx.x;          // one block per output row (N=4096 blocks)
    __shared__ float dsh[16];
    if (threadIdx.x < 16) dsh[threadIdx.x] = down[o * 16 + threadIdx.x];
    __syncthreads();
    float dr[16];
#pragma unroll
    for (int r = 0; r < 16; r++) dr[r] = dsh[r];

    for (int i = threadIdx.x * 4; i < IN; i += 256 * 4) {
        float4 w = *(const float4*)(W + (size_t)o * IN + i);
#pragma unroll
        for (int r = 0; r < 16; r++) {
            float4 u = *(const float4*)(up + r * IN + i);
            w.x += dr[r] * u.x; w.y += dr[r] * u.y;
            w.z += dr[r] * u.z; w.w += dr[r] * u.w;
        }
        union { unsigned short s[4]; uint2 v; } ov;
        ov.s[0] = f2bf_rne(w.x); ov.s[1] = f2bf_rne(w.y);
        ov.s[2] = f2bf_rne(w.z); ov.s[3] = f2bf_rne(w.w);
        *(uint2*)(wb + (size_t)o * IN + i) = ov.v;
    }
}

// ---------------- m97-style bf16 gemm_bt with bias ----------------
#define BM 128
#define BN 128
#define BK 32

static __device__ __forceinline__ void async16(const void* g, void* l) {
    auto* gp = reinterpret_cast<const __attribute__((address_space(1))) uint32_t*>(
        reinterpret_cast<uintptr_t>(g));
    auto* lp = reinterpret_cast<__attribute__((address_space(3))) uint32_t*>(
        reinterpret_cast<uintptr_t>(l));
    __builtin_amdgcn_global_load_lds(gp, lp, 16 /*bytes*/, 0, 0);
}

__global__ __launch_bounds__(256) void gemm_bt_bias_kernel(
    const unsigned short* __restrict__ A,   // bf16 [M][K]  (xb)
    const unsigned short* __restrict__ B,   // bf16 [N][K]  (wb)
    const float* __restrict__ bias,         // [N]
    float* __restrict__ C,                  // [M][N]
    int M, int N, int K) {
    __shared__ __align__(16) unsigned short As[BM * BK];
    __shared__ __align__(16) unsigned short Bs[BN * BK];

    const int tid  = threadIdx.x;
    const int wave = tid >> 6;
    const int lane = tid & 63;
    const int wm   = wave >> 1;      // wave row quadrant (0..1)
    const int wn   = wave & 1;       // wave col quadrant (0..1)
    const int quad = lane >> 4;      // 0..3
    const int l16  = lane & 15;

    const int tileM = blockIdx.y * BM;
    const int tileN = blockIdx.x * BN;

    // staging: each thread DMAs 16 B (8 bf16). row = tid/4, col8 = (tid%4)*8.
    const int srow = tid >> 2;
    const int scol = (tid & 3) * 8;

    const unsigned short* aptr0 = A + (size_t)(tileM + srow) * K + scol;
    const unsigned short* aptr1 = aptr0 + (size_t)64 * K;
    const unsigned short* bptr0 = B + (size_t)(tileN + srow) * K + scol;
    const unsigned short* bptr1 = bptr0 + (size_t)64 * K;

    // wave-uniform LDS DMA bases (HW adds lane*16)
    char* asw0 = (char*)As + wave * 1024;
    char* asw1 = asw0 + 4096;
    char* bsw0 = (char*)Bs + wave * 1024;
    char* bsw1 = bsw0 + 4096;

    floatx4 acc[4][4];
#pragma unroll
    for (int i = 0; i < 4; i++)
#pragma unroll
        for (int j = 0; j < 4; j++) acc[i][j] = (floatx4)(0.0f);

    for (int k0 = 0; k0 < K; k0 += BK) {
        async16(aptr0, asw0);
        async16(aptr1, asw1);
        async16(bptr0, bsw0);
        async16(bptr1, bsw1);
        aptr0 += BK; aptr1 += BK; bptr0 += BK; bptr1 += BK;
        __syncthreads();   // compiler emits vmcnt(0) drain before barrier

        bf16x8 af[4], bfr[4];
#pragma unroll
        for (int t = 0; t < 4; t++) {
            af[t]  = *(const bf16x8*)(As + (wm * 64 + t * 16 + l16) * BK + quad * 8);
            bfr[t] = *(const bf16x8*)(Bs + (wn * 64 + t * 16 + l16) * BK + quad * 8);
        }
#pragma unroll
        for (int i = 0; i < 4; i++)
#pragma unroll
            for (int j = 0; j < 4; j++)
                acc[i][j] = __builtin_amdgcn_mfma_f32_16x16x32_bf16(af[i], bfr[j],
                                                                   acc[i][j], 0, 0, 0);
        __syncthreads();
    }

    // epilogue: C[m][n] = acc + bias[n].  C/D layout: col=lane&15, row=quad*4+reg.
    float bv[4];
#pragma unroll
    for (int j = 0; j < 4; j++) bv[j] = bias[tileN + wn * 64 + j * 16 + l16];

#pragma unroll
    for (int i = 0; i < 4; i++) {
#pragma unroll
        for (int r = 0; r < 4; r++) {
            const int row = tileM + wm * 64 + i * 16 + quad * 4 + r;
            float* crow = C + (size_t)row * N + tileN + wn * 64 + l16;
#pragma unroll
            for (int j = 0; j < 4; j++) crow[j * 16] = acc[i][j][r] + bv[j];
        }
    }
}

extern "C" void kernel_launch(void* const* d_in, const int* in_sizes, int n_in,
                              void* d_out, int out_size, void* d_ws, size_t ws_size,
                              hipStream_t stream) {
    const float* x    = (const float*)d_in[0];
    const float* W    = (const float*)d_in[1];
    const float* bias = (const float*)d_in[2];
    const float* down = (const float*)d_in[3];
    const float* up   = (const float*)d_in[4];
    float* out = (float*)d_out;

    const int IN  = 4096;                 // K
    const int OUT = 4096;                 // N
    const int M   = in_sizes[0] / IN;     // 8192

    unsigned short* xb = (unsigned short*)d_ws;                  // M*K bf16 = 67 MB
    unsigned short* wb = xb + (size_t)M * IN;                    // N*K bf16 = 33.5 MB

    const int nx = M * IN;
    cvt_x_kernel<<<(nx / 8 + 255) / 256, 256, 0, stream>>>(x, xb, nx);
    merge_w_kernel<<<OUT, 256, 0, stream>>>(W, down, up, wb, IN);

    dim3 grid(OUT / BN, M / BM);   // (32, 64)
    gemm_bt_bias_kernel<<<grid, 256, 0, stream>>>(xb, wb, bias, out, M, OUT, IN);
}

// Round 2
// 615.824 us; speedup vs baseline: 1.0560x; 1.0560x over previous
//
#include <hip/hip_runtime.h>
#include <hip/hip_bf16.h>
#include <stdint.h>

// out[m,n] = sum_k x[m,k] * (W[n,k] + sum_r down[n,r]*up[r,k]) + bias[n]
// M=8192, N=4096, K=4096, R=16, fp32 I/O.
// bf16 MFMA gemm_bt (m97 structure) + XOR-swizzled LDS (kills 4-way phase
// conflicts) + register-cached LoRA merge + wide x conversion.

typedef __attribute__((ext_vector_type(4))) float  floatx4;
typedef __attribute__((ext_vector_type(8))) __bf16 bf16x8;

static __device__ __forceinline__ unsigned short f2bf_rne(float f) {
    union { float f; uint32_t u; } v; v.f = f;
    uint32_t r = v.u + 0x7fffu + ((v.u >> 16) & 1u);
    return (unsigned short)(r >> 16);
}

// ---------------- x fp32 -> bf16 (16 elems/thread) ----------------
__global__ __launch_bounds__(256) void cvt_x_kernel(const float* __restrict__ x,
                                                    unsigned short* __restrict__ xb,
                                                    int n) {
    int i = (blockIdx.x * 256 + threadIdx.x) * 16;
    if (i >= n) return;
    const float4* p = (const float4*)(x + i);
    float4 a = p[0], b = p[1], c = p[2], d = p[3];
    union { unsigned short s[8]; uint4 v; } o0, o1;
    o0.s[0] = f2bf_rne(a.x); o0.s[1] = f2bf_rne(a.y);
    o0.s[2] = f2bf_rne(a.z); o0.s[3] = f2bf_rne(a.w);
    o0.s[4] = f2bf_rne(b.x); o0.s[5] = f2bf_rne(b.y);
    o0.s[6] = f2bf_rne(b.z); o0.s[7] = f2bf_rne(b.w);
    o1.s[0] = f2bf_rne(c.x); o1.s[1] = f2bf_rne(c.y);
    o1.s[2] = f2bf_rne(c.z); o1.s[3] = f2bf_rne(c.w);
    o1.s[4] = f2bf_rne(d.x); o1.s[5] = f2bf_rne(d.y);
    o1.s[6] = f2bf_rne(d.z); o1.s[7] = f2bf_rne(d.w);
    *(uint4*)(xb + i) = o0.v;
    *(uint4*)(xb + i + 8) = o1.v;
}

// ------------- merged weight: Wb[n,k] = bf16(W[n,k] + sum_r d[n,r]*up[r,k]) -------------
// Block owns a 1024-col strip; caches its up-columns in registers (16 float4/thread);
// iterates MW_ROWS output rows. grid = (IN/1024, OUT/MW_ROWS).
#define MW_ROWS 16
__global__ __launch_bounds__(256) void merge_w_kernel(const float* __restrict__ W,
                                                      const float* __restrict__ down,
                                                      const float* __restrict__ up,
                                                      unsigned short* __restrict__ wb,
                                                      int IN) {
    const int i  = blockIdx.x * 1024 + threadIdx.x * 4;
    const int o0 = blockIdx.y * MW_ROWS;

    float4 u[16];
#pragma unroll
    for (int r = 0; r < 16; r++) u[r] = *(const float4*)(up + r * IN + i);

    for (int o = o0; o < o0 + MW_ROWS; o++) {
        float4 w = *(const float4*)(W + (size_t)o * IN + i);
#pragma unroll
        for (int r = 0; r < 16; r++) {
            const float dr = down[o * 16 + r];   // wave-uniform -> scalar load
            w.x += dr * u[r].x; w.y += dr * u[r].y;
            w.z += dr * u[r].z; w.w += dr * u[r].w;
        }
        union { unsigned short s[4]; uint2 v; } ov;
        ov.s[0] = f2bf_rne(w.x); ov.s[1] = f2bf_rne(w.y);
        ov.s[2] = f2bf_rne(w.z); ov.s[3] = f2bf_rne(w.w);
        *(uint2*)(wb + (size_t)o * IN + i) = ov.v;
    }
}

// ---------------- bf16 gemm_bt with bias, XOR-swizzled LDS ----------------
#define BM 128
#define BN 128
#define BK 32

static __device__ __forceinline__ void async16(const void* g, void* l) {
    auto* gp = reinterpret_cast<const __attribute__((address_space(1))) uint32_t*>(
        reinterpret_cast<uintptr_t>(g));
    auto* lp = reinterpret_cast<__attribute__((address_space(3))) uint32_t*>(
        reinterpret_cast<uintptr_t>(l));
    __builtin_amdgcn_global_load_lds(gp, lp, 16 /*bytes*/, 0, 0);
}

__global__ __launch_bounds__(256) void gemm_bt_bias_kernel(
    const unsigned short* __restrict__ A,   // bf16 [M][K]  (xb)
    const unsigned short* __restrict__ B,   // bf16 [N][K]  (wb)
    const float* __restrict__ bias,         // [N]
    float* __restrict__ C,                  // [M][N]
    int M, int N, int K) {
    __shared__ __align__(16) unsigned short As[BM * BK];
    __shared__ __align__(16) unsigned short Bs[BN * BK];

    const int tid  = threadIdx.x;
    const int wave = tid >> 6;
    const int lane = tid & 63;
    const int wm   = wave >> 1;
    const int wn   = wave & 1;
    const int quad = lane >> 4;      // 0..3
    const int l16  = lane & 15;

    const int tileM = blockIdx.y * BM;
    const int tileN = blockIdx.x * BN;

    // Staging: LDS slot s = tid holds fragment (row = s>>2, col' = s&3).
    // XOR swizzle: slot col' stores global quad  q = col' ^ ((row>>1)&3),
    // so lane loads global column ((tid&3) ^ ((tid>>3)&3))*8 of row tid>>2.
    const int srow = tid >> 2;
    const int scol = ((tid & 3) ^ ((tid >> 3) & 3)) * 8;

    const unsigned short* aptr0 = A + (size_t)(tileM + srow) * K + scol;
    const unsigned short* aptr1 = aptr0 + (size_t)64 * K;
    const unsigned short* bptr0 = B + (size_t)(tileN + srow) * K + scol;
    const unsigned short* bptr1 = bptr0 + (size_t)64 * K;

    // wave-uniform LDS DMA bases (HW adds lane*16)
    char* asw0 = (char*)As + wave * 1024;
    char* asw1 = asw0 + 4096;
    char* bsw0 = (char*)Bs + wave * 1024;
    char* bsw1 = bsw0 + 4096;

    // Read-side swizzle: fragment (row, quad) lives at col quad ^ ((row>>1)&3);
    // row = base16 + l16 (base16 multiple of 16) -> swz = (l16>>1)&3.
    const int aswz = (quad ^ ((l16 >> 1) & 3)) * 8;

    floatx4 acc[4][4];
#pragma unroll
    for (int i = 0; i < 4; i++)
#pragma unroll
        for (int j = 0; j < 4; j++) acc[i][j] = (floatx4)(0.0f);

    for (int k0 = 0; k0 < K; k0 += BK) {
        async16(aptr0, asw0);
        async16(aptr1, asw1);
        async16(bptr0, bsw0);
        async16(bptr1, bsw1);
        aptr0 += BK; aptr1 += BK; bptr0 += BK; bptr1 += BK;
        __syncthreads();

        bf16x8 af[4], bfr[4];
#pragma unroll
        for (int t = 0; t < 4; t++) {
            af[t]  = *(const bf16x8*)(As + (wm * 64 + t * 16 + l16) * BK + aswz);
            bfr[t] = *(const bf16x8*)(Bs + (wn * 64 + t * 16 + l16) * BK + aswz);
        }
#pragma unroll
        for (int i = 0; i < 4; i++)
#pragma unroll
            for (int j = 0; j < 4; j++)
                acc[i][j] = __builtin_amdgcn_mfma_f32_16x16x32_bf16(af[i], bfr[j],
                                                                   acc[i][j], 0, 0, 0);
        __syncthreads();
    }

    // epilogue: C/D layout col=lane&15, row=quad*4+reg.
    float bv[4];
#pragma unroll
    for (int j = 0; j < 4; j++) bv[j] = bias[tileN + wn * 64 + j * 16 + l16];

#pragma unroll
    for (int i = 0; i < 4; i++) {
#pragma unroll
        for (int r = 0; r < 4; r++) {
            const int row = tileM + wm * 64 + i * 16 + quad * 4 + r;
            float* crow = C + (size_t)row * N + tileN + wn * 64 + l16;
#pragma unroll
            for (int j = 0; j < 4; j++) crow[j * 16] = acc[i][j][r] + bv[j];
        }
    }
}

extern "C" void kernel_launch(void* const* d_in, const int* in_sizes, int n_in,
                              void* d_out, int out_size, void* d_ws, size_t ws_size,
                              hipStream_t stream) {
    const float* x    = (const float*)d_in[0];
    const float* W    = (const float*)d_in[1];
    const float* bias = (const float*)d_in[2];
    const float* down = (const float*)d_in[3];
    const float* up   = (const float*)d_in[4];
    float* out = (float*)d_out;

    const int IN  = 4096;                 // K
    const int OUT = 4096;                 // N
    const int M   = in_sizes[0] / IN;     // 8192

    unsigned short* xb = (unsigned short*)d_ws;                  // M*K bf16
    unsigned short* wb = xb + (size_t)M * IN;                    // N*K bf16

    const int nx = M * IN;
    cvt_x_kernel<<<nx / 16 / 256, 256, 0, stream>>>(x, xb, nx);
    dim3 mgrid(IN / 1024, OUT / MW_ROWS);   // (4, 256)
    merge_w_kernel<<<mgrid, 256, 0, stream>>>(W, down, up, wb, IN);

    dim3 grid(OUT / BN, M / BM);   // (32, 64)
    gemm_bt_bias_kernel<<<grid, 256, 0, stream>>>(xb, wb, bias, out, M, OUT, IN);
}

// Round 3
// 562.423 us; speedup vs baseline: 1.1563x; 1.0949x over previous
//
#include <hip/hip_runtime.h>
#include <hip/hip_bf16.h>
#include <stdint.h>

// out[m,n] = sum_k x[m,k] * (W[n,k] + sum_r down[n,r]*up[r,k]) + bias[n]
// M=8192, N=4096, K=4096, R=16, fp32 I/O.
// Round 3: BK=64 gemm (half the barrier drains), granule-XOR LDS swizzle
// (g = q ^ (row&7)) to keep 128B rows conflict-free; coalesced cvt.

typedef __attribute__((ext_vector_type(4))) float  floatx4;
typedef __attribute__((ext_vector_type(8))) __bf16 bf16x8;

static __device__ __forceinline__ unsigned short f2bf_rne(float f) {
    union { float f; uint32_t u; } v; v.f = f;
    uint32_t r = v.u + 0x7fffu + ((v.u >> 16) & 1u);
    return (unsigned short)(r >> 16);
}

// ---------------- x fp32 -> bf16, fully coalesced (float4 -> uint2) ----------------
__global__ __launch_bounds__(256) void cvt_x_kernel(const float4* __restrict__ x4,
                                                    uint2* __restrict__ o2,
                                                    int n4) {
    const int stride = gridDim.x * 256;
    for (int i = blockIdx.x * 256 + threadIdx.x; i < n4; i += stride) {
        float4 a = x4[i];
        union { unsigned short s[4]; uint2 v; } o;
        o.s[0] = f2bf_rne(a.x); o.s[1] = f2bf_rne(a.y);
        o.s[2] = f2bf_rne(a.z); o.s[3] = f2bf_rne(a.w);
        o2[i] = o.v;
    }
}

// ------------- merged weight: Wb[n,k] = bf16(W[n,k] + sum_r d[n,r]*up[r,k]) -------------
#define MW_ROWS 16
__global__ __launch_bounds__(256) void merge_w_kernel(const float* __restrict__ W,
                                                      const float* __restrict__ down,
                                                      const float* __restrict__ up,
                                                      unsigned short* __restrict__ wb,
                                                      int IN) {
    const int i  = blockIdx.x * 1024 + threadIdx.x * 4;
    const int o0 = blockIdx.y * MW_ROWS;

    float4 u[16];
#pragma unroll
    for (int r = 0; r < 16; r++) u[r] = *(const float4*)(up + r * IN + i);

    for (int o = o0; o < o0 + MW_ROWS; o++) {
        float4 w = *(const float4*)(W + (size_t)o * IN + i);
#pragma unroll
        for (int r = 0; r < 16; r++) {
            const float dr = down[o * 16 + r];   // wave-uniform -> scalar load
            w.x += dr * u[r].x; w.y += dr * u[r].y;
            w.z += dr * u[r].z; w.w += dr * u[r].w;
        }
        union { unsigned short s[4]; uint2 v; } ov;
        ov.s[0] = f2bf_rne(w.x); ov.s[1] = f2bf_rne(w.y);
        ov.s[2] = f2bf_rne(w.z); ov.s[3] = f2bf_rne(w.w);
        *(uint2*)(wb + (size_t)o * IN + i) = ov.v;
    }
}

// ---------------- bf16 gemm_bt, BK=64, granule-XOR swizzle ----------------
// LDS tile: 128 rows x 64 bf16 = 128 B/row = 8 granules of 16 B.
// Fragment (row, q) (global k-chunk q*8..q*8+8) stored at granule q ^ (row&7).
// DMA: instr s, wave w covers rows w*32+s*8 .. +8; lane l -> row +(l>>3),
//      granule l&7  => global chunk q = (l&7) ^ (l>>3)  (uniform across w,s).
// Read: ds_read_b128 at row*128 + ((h*4+quad)^(l16&7))*16 — any 8 consecutive
//      lanes hit 8 distinct granules => conflict-free.
#define BM 128
#define BN 128
#define BK 64

static __device__ __forceinline__ void async16(const void* g, void* l) {
    auto* gp = reinterpret_cast<const __attribute__((address_space(1))) uint32_t*>(
        reinterpret_cast<uintptr_t>(g));
    auto* lp = reinterpret_cast<__attribute__((address_space(3))) uint32_t*>(
        reinterpret_cast<uintptr_t>(l));
    __builtin_amdgcn_global_load_lds(gp, lp, 16 /*bytes*/, 0, 0);
}

__global__ __launch_bounds__(256) void gemm_bt_bias_kernel(
    const unsigned short* __restrict__ A,   // bf16 [M][K]  (xb)
    const unsigned short* __restrict__ B,   // bf16 [N][K]  (wb)
    const float* __restrict__ bias,         // [N]
    float* __restrict__ C,                  // [M][N]
    int M, int N, int K) {
    __shared__ __align__(16) unsigned short As[BM * BK];
    __shared__ __align__(16) unsigned short Bs[BN * BK];

    const int tid  = threadIdx.x;
    const int wave = tid >> 6;
    const int lane = tid & 63;
    const int wm   = wave >> 1;
    const int wn   = wave & 1;
    const int quad = lane >> 4;      // 0..3
    const int l16  = lane & 15;

    const int tileM = blockIdx.y * BM;
    const int tileN = blockIdx.x * BN;

    // DMA staging addresses
    const int rowoff = wave * 32 + ((lane >> 3) & 7);          // + s*8 per instr
    const int qcol   = ((lane & 7) ^ (lane >> 3)) * 8;         // element offset
    const unsigned short* aptr = A + (size_t)(tileM + rowoff) * K + qcol;
    const unsigned short* bptr = B + (size_t)(tileN + rowoff) * K + qcol;
    char* abase = (char*)As + wave * 4096;                     // + s*1024 per instr
    char* bbase = (char*)Bs + wave * 4096;

    floatx4 acc[4][4];
#pragma unroll
    for (int i = 0; i < 4; i++)
#pragma unroll
        for (int j = 0; j < 4; j++) acc[i][j] = (floatx4)(0.0f);

    for (int k0 = 0; k0 < K; k0 += BK) {
#pragma unroll
        for (int s = 0; s < 4; s++) {
            async16(aptr + (size_t)s * 8 * K, abase + s * 1024);
            async16(bptr + (size_t)s * 8 * K, bbase + s * 1024);
        }
        aptr += BK; bptr += BK;
        __syncthreads();

#pragma unroll
        for (int h = 0; h < 2; h++) {
            bf16x8 af[4], bfr[4];
#pragma unroll
            for (int t = 0; t < 4; t++) {
                const int arow = wm * 64 + t * 16 + l16;
                const int brow = wn * 64 + t * 16 + l16;
                af[t]  = *(const bf16x8*)((const char*)As + arow * 128 +
                                          (((h * 4 + quad) ^ (l16 & 7)) * 16));
                bfr[t] = *(const bf16x8*)((const char*)Bs + brow * 128 +
                                          (((h * 4 + quad) ^ (l16 & 7)) * 16));
            }
#pragma unroll
            for (int i = 0; i < 4; i++)
#pragma unroll
                for (int j = 0; j < 4; j++)
                    acc[i][j] = __builtin_amdgcn_mfma_f32_16x16x32_bf16(
                        af[i], bfr[j], acc[i][j], 0, 0, 0);
        }
        __syncthreads();
    }

    // epilogue: C/D layout col=lane&15, row=quad*4+reg.
    float bv[4];
#pragma unroll
    for (int j = 0; j < 4; j++) bv[j] = bias[tileN + wn * 64 + j * 16 + l16];

#pragma unroll
    for (int i = 0; i < 4; i++) {
#pragma unroll
        for (int r = 0; r < 4; r++) {
            const int row = tileM + wm * 64 + i * 16 + quad * 4 + r;
            float* crow = C + (size_t)row * N + tileN + wn * 64 + l16;
#pragma unroll
            for (int j = 0; j < 4; j++) crow[j * 16] = acc[i][j][r] + bv[j];
        }
    }
}

extern "C" void kernel_launch(void* const* d_in, const int* in_sizes, int n_in,
                              void* d_out, int out_size, void* d_ws, size_t ws_size,
                              hipStream_t stream) {
    const float* x    = (const float*)d_in[0];
    const float* W    = (const float*)d_in[1];
    const float* bias = (const float*)d_in[2];
    const float* down = (const float*)d_in[3];
    const float* up   = (const float*)d_in[4];
    float* out = (float*)d_out;

    const int IN  = 4096;                 // K
    const int OUT = 4096;                 // N
    const int M   = in_sizes[0] / IN;     // 8192

    unsigned short* xb = (unsigned short*)d_ws;                  // M*K bf16
    unsigned short* wb = xb + (size_t)M * IN;                    // N*K bf16

    const int n4 = M * IN / 4;
    cvt_x_kernel<<<n4 / 2 / 256, 256, 0, stream>>>((const float4*)x, (uint2*)xb, n4);
    dim3 mgrid(IN / 1024, OUT / MW_ROWS);   // (4, 256)
    merge_w_kernel<<<mgrid, 256, 0, stream>>>(W, down, up, wb, IN);

    dim3 grid(OUT / BN, M / BM);   // (32, 64)
    gemm_bt_bias_kernel<<<grid, 256, 0, stream>>>(xb, wb, bias, out, M, OUT, IN);
}